// Round 5
// baseline (235.411 us; speedup 1.0000x reference)
//
#include <hip/hip_runtime.h>
#include <stdint.h>

#define TOKENS  256
#define INF     4096
#define OUTF    11008
#define NGROUPS 32
#define NTH     256

// R5 geometry: block tile 128x128, K-split 8 (512 K per block), phase k=64.
#define KSPLIT  8
#define KBLK    (INF / KSPLIT)     // 512
#define PHK     64
#define NPH     (KBLK / PHK)       // 8

typedef __attribute__((ext_vector_type(2))) _Float16 f16x2;
typedef __attribute__((ext_vector_type(8))) _Float16 f16x8;
typedef __attribute__((ext_vector_type(2))) __fp16   pkh2;
typedef __attribute__((ext_vector_type(4))) float    f32x4;

union U32H2 { uint32_t u; f16x2 h; };
union H8    { f16x2 h2[4]; f16x8 h8; };
union PK    { pkh2 p; f16x2 h; };

__device__ __forceinline__ void gl2lds16(const void* g, void* l) {
    __builtin_amdgcn_global_load_lds(
        (const __attribute__((address_space(1))) uint32_t*)g,
        (__attribute__((address_space(3))) uint32_t*)l, 16, 0, 0);
}

// ---------------- pre-kernel 1: x fp32 -> fp16, (j, j+4) pair-permuted -------
__global__ __launch_bounds__(NTH)
void cvt_x(const float* __restrict__ x, _Float16* __restrict__ x16) {
    const int t   = blockIdx.x * NTH + threadIdx.x;   // 0 .. 131071
    const int row = t >> 9;
    const int c   = t & 511;
    const float* p = x + (size_t)row * INF + c * 8;
    f32x4 v0 = *(const f32x4*)p;
    f32x4 v1 = *(const f32x4*)(p + 4);
    H8 o; PK k0, k1, k2, k3;
    k0.p = __builtin_amdgcn_cvt_pkrtz(v0[0], v1[0]);
    k1.p = __builtin_amdgcn_cvt_pkrtz(v0[1], v1[1]);
    k2.p = __builtin_amdgcn_cvt_pkrtz(v0[2], v1[2]);
    k3.p = __builtin_amdgcn_cvt_pkrtz(v0[3], v1[3]);
    o.h2[0] = k0.h; o.h2[1] = k1.h; o.h2[2] = k2.h; o.h2[3] = k3.h;
    *(f16x8*)(x16 + (size_t)row * INF + c * 8) = o.h8;
}

// ---------------- pre-kernel 2: out := broadcast(bias) -----------------------
// 704512 float4 = 2752 blocks x 256 threads exactly.
__global__ __launch_bounds__(NTH)
void init_out(const float* __restrict__ bias, float* __restrict__ out) {
    const int idx = blockIdx.x * NTH + threadIdx.x;      // float4 index
    const int c4  = idx - (idx / (OUTF / 4)) * (OUTF / 4);
    ((f32x4*)out)[idx] = ((const f32x4*)bias)[c4];
}

// ---------------- main kernel ------------------------------------------------
// grid = 86 (bx) x 2 (by) x 8 (kh) = 1376 blocks, 256 threads (2x2 waves).
// Wave tile 64x64 (mi=4, nf=4). A staged in LDS (32KB dbuf), B dequanted
// in-register from global. Partials atomicAdd'ed onto bias-initialized out.
__global__ __launch_bounds__(NTH, 4)
void qlin_main(const _Float16* __restrict__ x16,
               const uint32_t* __restrict__ qweight,
               const uint32_t* __restrict__ qzeros,
               const float* __restrict__ scales,
               float* __restrict__ out)
{
    __shared__ alignas(16) _Float16 As[2][128 * PHK];   // 2 x 16KB

    const int tid = threadIdx.x;
    const int b   = blockIdx.x;
    const int kh  = b & 7;
    const int by  = (b >> 3) & 1;
    const int bx  = b >> 4;            // 0..85

    const int lane = tid & 63;
    const int quad = lane >> 4;
    const int l16  = lane & 15;
    const int wv   = tid >> 6;
    const int wr   = wv >> 1;          // row half  (0/1)
    const int wc   = wv & 1;           // col half  (0/1)

    // ---- A fill map: thread t writes LDS bytes [t*16, t*16+16) of each 4KB
    // round ii; source row = ii*32 + (t>>3), stored chunk = t&7,
    // logical chunk = stored ^ (row&7)  (XOR swizzle, read side matches). ----
    const int arow  = (tid >> 3);             // 0..31 within round
    const int lchk  = (tid & 7) ^ (arow & 7); // logical 16B chunk 0..7
    // global byte offset (excluding phase term): row*8192 + kh*1024 + lchk*16
    const char* x16b = (const char*)x16;
    uint32_t aoff[4];
#pragma unroll
    for (int ii = 0; ii < 4; ++ii)
        aoff[ii] = (uint32_t)((by * 128 + ii * 32 + arow) * (INF * 2)
                              + kh * (KBLK * 2) + lchk * 16);
    _Float16* ldsW = &As[0][0];
    const int ldsBase = wv * 512;      // halves; +ii*2048 per round; +8192 per buf

    // ---- B map: col strips ----
    int colN[4];
#pragma unroll
    for (int nf = 0; nf < 4; ++nf)
        colN[nf] = bx * 128 + wc * 64 + nf * 16 + l16;
    const int zsh = (colN[0] & 7) * 4;          // same for all nf (stride 16)
    const int qrow0 = kh * (KBLK / 8);          // first qweight row of this block

    f32x4 acc[4][4];
#pragma unroll
    for (int mi = 0; mi < 4; ++mi)
#pragma unroll
        for (int nf = 0; nf < 4; ++nf)
            acc[mi][nf] = f32x4{0.f, 0.f, 0.f, 0.f};

    uint32_t Breg[2][8];               // [par][s*4+nf]

    // ================= prologue: phase 0 =================
#pragma unroll
    for (int ii = 0; ii < 4; ++ii)
        gl2lds16(x16b + aoff[ii], ldsW + ii * 2048 + ldsBase);
#pragma unroll
    for (int s = 0; s < 2; ++s) {
        const uint32_t* qp = qweight + (size_t)(qrow0 + s * 4 + quad) * OUTF;
#pragma unroll
        for (int nf = 0; nf < 4; ++nf)
            Breg[0][s * 4 + nf] = qp[colN[nf]];
    }
    __syncthreads();

    // ================= phase loop (rolled 2x) =================
#define PHASE_BODY(PAR, P, DO_PREFETCH)                                         \
    {                                                                           \
        const int p_ = (P);                                                     \
        if (DO_PREFETCH) {                                                      \
            const int pn = p_ + 1;                                              \
            _Float16* ldsN = ldsW + (1 - (PAR)) * 8192;                         \
            _Pragma("unroll")                                                   \
            for (int ii = 0; ii < 4; ++ii)                                      \
                gl2lds16(x16b + aoff[ii] + pn * (PHK * 2),                      \
                         ldsN + ii * 2048 + ldsBase);                           \
            _Pragma("unroll")                                                   \
            for (int s = 0; s < 2; ++s) {                                       \
                const uint32_t* qp = qweight +                                  \
                    (size_t)(qrow0 + pn * 8 + s * 4 + quad) * OUTF;             \
                _Pragma("unroll")                                               \
                for (int nf = 0; nf < 4; ++nf)                                  \
                    Breg[1 - (PAR)][s * 4 + nf] = qp[colN[nf]];                 \
            }                                                                   \
        }                                                                       \
        /* per-phase group constants (group = 128k = 2 phases) */               \
        const int g_ = kh * (KBLK / 128) + (p_ >> 1);                           \
        f16x2 hs2[4], hz2[4];                                                   \
        _Pragma("unroll")                                                       \
        for (int nf = 0; nf < 4; ++nf) {                                        \
            const float s = scales[g_ * OUTF + colN[nf]];                       \
            const int   z = (int)((qzeros[g_ * (OUTF / 8) + (colN[nf] >> 3)]    \
                                   >> zsh) & 15u) + 1025;                       \
            const _Float16 hs = (_Float16)s;                                    \
            const _Float16 hz = (_Float16)(-(float)z);                          \
            hs2[nf] = f16x2{hs, hs};                                            \
            hz2[nf] = f16x2{hz, hz};                                            \
        }                                                                       \
        const _Float16* buf = ldsW + (PAR) * 8192;                              \
        _Pragma("unroll")                                                       \
        for (int s = 0; s < 2; ++s) {                                           \
            f16x8 af[4];                                                        \
            _Pragma("unroll")                                                   \
            for (int mi = 0; mi < 4; ++mi) {                                    \
                const int m  = wr * 64 + mi * 16 + l16;                         \
                const int sc = (s * 4 + quad) ^ (l16 & 7);                      \
                af[mi] = *(const f16x8*)(buf + m * PHK + sc * 8);               \
            }                                                                   \
            _Pragma("unroll")                                                   \
            for (int nf = 0; nf < 4; ++nf) {                                    \
                const uint32_t q = Breg[PAR][s * 4 + nf];                       \
                H8 bfr;                                                         \
                _Pragma("unroll")                                               \
                for (int j = 0; j < 4; ++j) {                                   \
                    U32H2 u;                                                    \
                    u.u = ((q >> (4 * j)) & 0x000F000Fu) | 0x64006400u;         \
                    bfr.h2[j] = (u.h + hz2[nf]) * hs2[nf];                      \
                }                                                               \
                _Pragma("unroll")                                               \
                for (int mi = 0; mi < 4; ++mi)                                  \
                    acc[mi][nf] = __builtin_amdgcn_mfma_f32_16x16x32_f16(       \
                        af[mi], bfr.h8, acc[mi][nf], 0, 0, 0);                  \
            }                                                                   \
        }                                                                       \
        __syncthreads();                                                        \
    }

#pragma unroll 1
    for (int pp = 0; pp < NPH / 2; ++pp) {
        PHASE_BODY(0, 2 * pp, true)
        PHASE_BODY(1, 2 * pp + 1, (pp < NPH / 2 - 1))
    }
#undef PHASE_BODY

    // ================= epilogue: atomic accumulate =================
#pragma unroll
    for (int nf = 0; nf < 4; ++nf) {
        const int col = colN[nf];
#pragma unroll
        for (int mi = 0; mi < 4; ++mi) {
            const int r0 = by * 128 + wr * 64 + mi * 16 + quad * 4;
#pragma unroll
            for (int rg = 0; rg < 4; ++rg)
                atomicAdd(&out[(size_t)(r0 + rg) * OUTF + col], acc[mi][nf][rg]);
        }
    }
}

// ---------------- fallback (proven R2 kernel) if ws too small ----------------
__global__ __launch_bounds__(NTH, 2)
void qlin_fb(const float* __restrict__ x,
             const uint32_t* __restrict__ qweight,
             const uint32_t* __restrict__ qzeros,
             const float* __restrict__ scales,
             const float* __restrict__ bias,
             float* __restrict__ out)
{
    __shared__ alignas(16) _Float16 Asb[64][40];
    __shared__ alignas(16) _Float16 Bsb[128][40];
    const int tid = threadIdx.x;
    const int bx = blockIdx.x, by = blockIdx.y;
    const int am = tid >> 2, ar = tid & 3;
    const float* xrow = x + (size_t)(by * 64 + am) * INF + ar * 8;
    const int bc = tid & 127, br = tid >> 7;
    const int bn = bx * 128 + bc;
    const int bswz = (bc >> 3) & 3;
    const int lane = tid & 63, quad = lane >> 4, l16 = lane & 15;
    const int wv = tid >> 6, wm = wv >> 1, wn = wv & 1;
    f32x4 acc[2][4];
#pragma unroll
    for (int i = 0; i < 2; ++i)
#pragma unroll
        for (int j = 0; j < 4; ++j) acc[i][j] = f32x4{0.f, 0.f, 0.f, 0.f};
    f32x4 pa0 = *(const f32x4*)(xrow + 0);
    f32x4 pa1 = *(const f32x4*)(xrow + 4);
    uint32_t pq0 = qweight[(size_t)br * OUTF + bn];
    uint32_t pq1 = qweight[(size_t)(br + 2) * OUTF + bn];
    for (int g = 0; g < NGROUPS; ++g) {
        const float s = scales[g * OUTF + bn];
        const uint32_t qzv = qzeros[g * (OUTF / 8) + (bn >> 3)];
        const int z = (int)((qzv >> (4 * (bn & 7))) & 15u) + 1;
        const _Float16 hs = (_Float16)s;
        const _Float16 hz = (_Float16)(-(float)(1024 + z));
        const f16x2 hs2 = {hs, hs}, hz2 = {hz, hz};
#pragma unroll
        for (int t4 = 0; t4 < 4; ++t4) {
            const int it = (g << 2) + t4;
            { H8 ah; PK p0, p1, p2, p3;
              p0.p = __builtin_amdgcn_cvt_pkrtz(pa0[0], pa1[0]);
              p1.p = __builtin_amdgcn_cvt_pkrtz(pa0[1], pa1[1]);
              p2.p = __builtin_amdgcn_cvt_pkrtz(pa0[2], pa1[2]);
              p3.p = __builtin_amdgcn_cvt_pkrtz(pa0[3], pa1[3]);
              ah.h2[0] = p0.h; ah.h2[1] = p1.h; ah.h2[2] = p2.h; ah.h2[3] = p3.h;
              *(f16x8*)&Asb[am][ar * 8] = ah.h8; }
            { const uint32_t qq[2] = {pq0, pq1};
#pragma unroll
              for (int rr = 0; rr < 2; ++rr) {
                  const int r = br + rr * 2; H8 bh;
#pragma unroll
                  for (int jp = 0; jp < 4; ++jp) {
                      U32H2 u; u.u = ((qq[rr] >> (4 * jp)) & 0x000F000Fu) | 0x64006400u;
                      bh.h2[jp] = (u.h + hz2) * hs2;
                  }
                  *(f16x8*)&Bsb[bc][(r ^ bswz) * 8] = bh.h8;
              } }
            __syncthreads();
            const int itn = (it < 127) ? it + 1 : 127;
            pa0 = *(const f32x4*)(xrow + itn * 32);
            pa1 = *(const f32x4*)(xrow + itn * 32 + 4);
            pq0 = qweight[(size_t)(itn * 4 + br) * OUTF + bn];
            pq1 = qweight[(size_t)(itn * 4 + br + 2) * OUTF + bn];
            f16x8 af[2], bf[4];
#pragma unroll
            for (int mi = 0; mi < 2; ++mi)
                af[mi] = *(const f16x8*)&Asb[wm * 32 + mi * 16 + l16][quad * 8];
#pragma unroll
            for (int ni = 0; ni < 4; ++ni) {
                const int c = wn * 64 + ni * 16 + l16;
                bf[ni] = *(const f16x8*)&Bsb[c][(quad ^ ((c >> 3) & 3)) * 8];
            }
#pragma unroll
            for (int mi = 0; mi < 2; ++mi)
#pragma unroll
                for (int ni = 0; ni < 4; ++ni)
                    acc[mi][ni] = __builtin_amdgcn_mfma_f32_16x16x32_f16(
                        af[mi], bf[ni], acc[mi][ni], 0, 0, 0);
            __syncthreads();
        }
    }
#pragma unroll
    for (int ni = 0; ni < 4; ++ni) {
        const int col = bx * 128 + wn * 64 + ni * 16 + l16;
        const float bv = bias[col];
#pragma unroll
        for (int mi = 0; mi < 2; ++mi) {
            const int row0 = by * 64 + wm * 32 + mi * 16 + quad * 4;
#pragma unroll
            for (int rg = 0; rg < 4; ++rg)
                out[(size_t)(row0 + rg) * OUTF + col] = acc[mi][ni][rg] + bv;
        }
    }
}

extern "C" void kernel_launch(void* const* d_in, const int* in_sizes, int n_in,
                              void* d_out, int out_size, void* d_ws, size_t ws_size,
                              hipStream_t stream) {
    const float*    xx = (const float*)d_in[0];
    const uint32_t* qw = (const uint32_t*)d_in[1];
    const uint32_t* qz = (const uint32_t*)d_in[2];
    const float*    sc = (const float*)d_in[3];
    const float*    bs = (const float*)d_in[4];
    float* out = (float*)d_out;

    const size_t x16_bytes = (size_t)TOKENS * INF * sizeof(_Float16);  // 2 MB
    if (ws_size >= x16_bytes) {
        _Float16* x16 = (_Float16*)d_ws;
        cvt_x<<<(TOKENS * INF / 8) / NTH, NTH, 0, stream>>>(xx, x16);
        init_out<<<(TOKENS * OUTF / 4) / NTH, NTH, 0, stream>>>(bs, out);
        qlin_main<<<(OUTF / 128) * 2 * KSPLIT, NTH, 0, stream>>>(x16, qw, qz, sc, out);
    } else {
        dim3 grid(OUTF / 128, TOKENS / 64);
        qlin_fb<<<grid, NTH, 0, stream>>>(xx, qw, qz, sc, bs, out);
    }
}

// Round 6
// 196.980 us; speedup vs baseline: 1.1951x; 1.1951x over previous
//
#include <hip/hip_runtime.h>
#include <stdint.h>

#define TOKENS  256
#define INF     4096
#define OUTF    11008
#define NGROUPS 32
#define NTH     256
#define NCHK    16          // K chunks of 256 (8 k-steps of 32)

typedef __attribute__((ext_vector_type(2))) _Float16 f16x2;
typedef __attribute__((ext_vector_type(8))) _Float16 f16x8;
typedef __attribute__((ext_vector_type(2))) __fp16   pkh2;
typedef __attribute__((ext_vector_type(4))) float    f32x4;

union U32H2 { uint32_t u; f16x2 h; };
union H8    { f16x2 h2[4]; f16x8 h8; };
union PK    { pkh2 p; f16x2 h; };

// ---------------- pre-kernel: x fp32 -> fp16, (j, j+4) pair-permuted ---------
__global__ __launch_bounds__(NTH)
void cvt_x(const float* __restrict__ x, _Float16* __restrict__ x16) {
    const int t   = blockIdx.x * NTH + threadIdx.x;   // 0 .. 131071
    const int row = t >> 9;
    const int c   = t & 511;
    const float* p = x + (size_t)row * INF + c * 8;
    f32x4 v0 = *(const f32x4*)p;
    f32x4 v1 = *(const f32x4*)(p + 4);
    H8 o; PK k0, k1, k2, k3;
    k0.p = __builtin_amdgcn_cvt_pkrtz(v0[0], v1[0]);
    k1.p = __builtin_amdgcn_cvt_pkrtz(v0[1], v1[1]);
    k2.p = __builtin_amdgcn_cvt_pkrtz(v0[2], v1[2]);
    k3.p = __builtin_amdgcn_cvt_pkrtz(v0[3], v1[3]);
    o.h2[0] = k0.h; o.h2[1] = k1.h; o.h2[2] = k2.h; o.h2[3] = k3.h;
    *(f16x8*)(x16 + (size_t)row * INF + c * 8) = o.h8;
}

// ---------------- main kernel: NO LDS, NO BARRIERS ---------------------------
// R3-R5 lesson: every __syncthreads() drains vmcnt(0), exposing ~900cyc of the
// in-flight B prefetch each phase (the m97-plateau mechanism). x16 is 2MB and
// L2-resident, so A-fragments are read directly from global (16 x 64B coalesced
// segments per frag load, L1-hot across the 4 waves sharing rows). B is
// dequanted in-register from a double-buffered k=256 prefetch. Zero barriers:
// the compiler keeps loads in flight across chunks with per-register vmcnt(N).
// Block = 4 independent waves; wave tile 64 rows x 32 cols (mi=4, nf=2).
__global__ __launch_bounds__(NTH, 3)
void qlin_main(const _Float16* __restrict__ x16,
               const uint32_t* __restrict__ qweight,
               const uint32_t* __restrict__ qzeros,
               const float* __restrict__ scales,
               const float* __restrict__ bias,
               float* __restrict__ out)
{
    const int tid = threadIdx.x;
    const int bx  = blockIdx.x >> 2;   // 0..85
    const int by  = blockIdx.x & 3;    // 0..3

    const int lane = tid & 63;
    const int quad = lane >> 4;
    const int l16  = lane & 15;
    const int wv   = tid >> 6;         // 0..3 : 32-col strip

    // ---- A fragment bases: row = by*64 + mi*16 + l16, k-offset quad*8 ----
    // frag(mi, kstep) = 16B at abase + mi*(16*INF) + kstep*32   (halves)
    const _Float16* abase = x16 + (size_t)(by * 64 + l16) * INF + quad * 8;

    // ---- B columns ----
    const int col0 = bx * 128 + wv * 32 + l16;    // nf=0
    const int col1 = col0 + 16;                   // nf=1
    const int zsh  = (col0 & 7) * 4;              // same for col1

    f32x4 acc[4][2];
#pragma unroll
    for (int mi = 0; mi < 4; ++mi)
#pragma unroll
        for (int nf = 0; nf < 2; ++nf)
            acc[mi][nf] = f32x4{0.f, 0.f, 0.f, 0.f};

    uint32_t Breg[2][16];   // [buf][s*2+nf] : one chunk = 8 ksteps x 2 cols
    float    sSc[2][4];     // [buf][gh*2+nf] : 2 groups per chunk
    uint32_t qZr[2][4];

    // ================= prologue: chunk 0 B + groups 0,1 =================
#pragma unroll
    for (int s = 0; s < 8; ++s) {
        const uint32_t* qp = qweight + (size_t)(s * 4 + quad) * OUTF;
        Breg[0][s * 2 + 0] = qp[col0];
        Breg[0][s * 2 + 1] = qp[col1];
    }
    sSc[0][0] = scales[0 * OUTF + col0]; sSc[0][1] = scales[0 * OUTF + col1];
    sSc[0][2] = scales[1 * OUTF + col0]; sSc[0][3] = scales[1 * OUTF + col1];
    qZr[0][0] = qzeros[0 * (OUTF / 8) + (col0 >> 3)]; qZr[0][1] = qzeros[0 * (OUTF / 8) + (col1 >> 3)];
    qZr[0][2] = qzeros[1 * (OUTF / 8) + (col0 >> 3)]; qZr[0][3] = qzeros[1 * (OUTF / 8) + (col1 >> 3)];

    // ================= chunk loop (rolled 2x; PAR compile-time) =================
#define CHUNK_BODY(PAR, CH)                                                     \
    {                                                                           \
        const int ch_ = (CH);                                                   \
        /* prefetch next chunk into buf 1-PAR (clamped on last; stays in flight \
           across the whole current chunk -- no barrier ever drains it) */      \
        const int pn = (ch_ < NCHK - 1) ? ch_ + 1 : NCHK - 1;                   \
        {                                                                       \
            const uint32_t* qpb = qweight + (size_t)(pn * 32 + quad) * OUTF;    \
            _Pragma("unroll")                                                   \
            for (int s = 0; s < 8; ++s) {                                       \
                const uint32_t* qp = qpb + (size_t)(s * 4) * OUTF;              \
                Breg[1 - (PAR)][s * 2 + 0] = qp[col0];                          \
                Breg[1 - (PAR)][s * 2 + 1] = qp[col1];                          \
            }                                                                   \
            const int g0 = 2 * pn, g1 = 2 * pn + 1;                             \
            sSc[1 - (PAR)][0] = scales[g0 * OUTF + col0];                       \
            sSc[1 - (PAR)][1] = scales[g0 * OUTF + col1];                       \
            sSc[1 - (PAR)][2] = scales[g1 * OUTF + col0];                       \
            sSc[1 - (PAR)][3] = scales[g1 * OUTF + col1];                       \
            qZr[1 - (PAR)][0] = qzeros[g0 * (OUTF / 8) + (col0 >> 3)];          \
            qZr[1 - (PAR)][1] = qzeros[g0 * (OUTF / 8) + (col1 >> 3)];          \
            qZr[1 - (PAR)][2] = qzeros[g1 * (OUTF / 8) + (col0 >> 3)];          \
            qZr[1 - (PAR)][3] = qzeros[g1 * (OUTF / 8) + (col1 >> 3)];          \
        }                                                                       \
        /* per-chunk dequant constants (2 groups x 2 cols) */                   \
        f16x2 hs2[2][2], hz2[2][2];                                             \
        _Pragma("unroll")                                                       \
        for (int gh = 0; gh < 2; ++gh)                                          \
            _Pragma("unroll")                                                   \
            for (int nf = 0; nf < 2; ++nf) {                                    \
                const float s = sSc[PAR][gh * 2 + nf];                          \
                const int   z = (int)((qZr[PAR][gh * 2 + nf] >> zsh) & 15u)     \
                                + 1025;                                         \
                const _Float16 hs = (_Float16)s;                                \
                const _Float16 hz = (_Float16)(-(float)z);                      \
                hs2[gh][nf] = f16x2{hs, hs};                                    \
                hz2[gh][nf] = f16x2{hz, hz};                                    \
            }                                                                   \
        _Pragma("unroll")                                                       \
        for (int s = 0; s < 8; ++s) {                                           \
            const int kstep = ch_ * 8 + s;                                      \
            const int gh = s >> 2;                                              \
            f16x8 af[4];                                                        \
            _Pragma("unroll")                                                   \
            for (int mi = 0; mi < 4; ++mi)                                      \
                af[mi] = *(const f16x8*)(abase + (size_t)mi * (16 * INF)        \
                                         + kstep * 32);                         \
            _Pragma("unroll")                                                   \
            for (int nf = 0; nf < 2; ++nf) {                                    \
                const uint32_t q = Breg[PAR][s * 2 + nf];                       \
                H8 bfr;                                                         \
                _Pragma("unroll")                                               \
                for (int j = 0; j < 4; ++j) {                                   \
                    U32H2 u;                                                    \
                    u.u = ((q >> (4 * j)) & 0x000F000Fu) | 0x64006400u;         \
                    bfr.h2[j] = (u.h + hz2[gh][nf]) * hs2[gh][nf];              \
                }                                                               \
                _Pragma("unroll")                                               \
                for (int mi = 0; mi < 4; ++mi)                                  \
                    acc[mi][nf] = __builtin_amdgcn_mfma_f32_16x16x32_f16(       \
                        af[mi], bfr.h8, acc[mi][nf], 0, 0, 0);                  \
            }                                                                   \
        }                                                                       \
    }

#pragma unroll 1
    for (int pp = 0; pp < NCHK / 2; ++pp) {
        CHUNK_BODY(0, 2 * pp)
        CHUNK_BODY(1, 2 * pp + 1)
    }
#undef CHUNK_BODY

    // ================= epilogue: direct store + bias =================
#pragma unroll
    for (int nf = 0; nf < 2; ++nf) {
        const int col = (nf == 0) ? col0 : col1;
        const float bv = bias[col];
#pragma unroll
        for (int mi = 0; mi < 4; ++mi) {
            const int r0 = by * 64 + mi * 16 + quad * 4;
#pragma unroll
            for (int rg = 0; rg < 4; ++rg)
                out[(size_t)(r0 + rg) * OUTF + col] = acc[mi][nf][rg] + bv;
        }
    }
}

// ---------------- fallback (proven R2 kernel) if ws too small ----------------
__global__ __launch_bounds__(NTH, 2)
void qlin_fb(const float* __restrict__ x,
             const uint32_t* __restrict__ qweight,
             const uint32_t* __restrict__ qzeros,
             const float* __restrict__ scales,
             const float* __restrict__ bias,
             float* __restrict__ out)
{
    __shared__ alignas(16) _Float16 Asb[64][40];
    __shared__ alignas(16) _Float16 Bsb[128][40];
    const int tid = threadIdx.x;
    const int bx = blockIdx.x, by = blockIdx.y;
    const int am = tid >> 2, ar = tid & 3;
    const float* xrow = x + (size_t)(by * 64 + am) * INF + ar * 8;
    const int bc = tid & 127, br = tid >> 7;
    const int bn = bx * 128 + bc;
    const int bswz = (bc >> 3) & 3;
    const int lane = tid & 63, quad = lane >> 4, l16 = lane & 15;
    const int wv = tid >> 6, wm = wv >> 1, wn = wv & 1;
    f32x4 acc[2][4];
#pragma unroll
    for (int i = 0; i < 2; ++i)
#pragma unroll
        for (int j = 0; j < 4; ++j) acc[i][j] = f32x4{0.f, 0.f, 0.f, 0.f};
    f32x4 pa0 = *(const f32x4*)(xrow + 0);
    f32x4 pa1 = *(const f32x4*)(xrow + 4);
    uint32_t pq0 = qweight[(size_t)br * OUTF + bn];
    uint32_t pq1 = qweight[(size_t)(br + 2) * OUTF + bn];
    for (int g = 0; g < NGROUPS; ++g) {
        const float s = scales[g * OUTF + bn];
        const uint32_t qzv = qzeros[g * (OUTF / 8) + (bn >> 3)];
        const int z = (int)((qzv >> (4 * (bn & 7))) & 15u) + 1;
        const _Float16 hs = (_Float16)s;
        const _Float16 hz = (_Float16)(-(float)(1024 + z));
        const f16x2 hs2 = {hs, hs}, hz2 = {hz, hz};
#pragma unroll
        for (int t4 = 0; t4 < 4; ++t4) {
            const int it = (g << 2) + t4;
            { H8 ah; PK p0, p1, p2, p3;
              p0.p = __builtin_amdgcn_cvt_pkrtz(pa0[0], pa1[0]);
              p1.p = __builtin_amdgcn_cvt_pkrtz(pa0[1], pa1[1]);
              p2.p = __builtin_amdgcn_cvt_pkrtz(pa0[2], pa1[2]);
              p3.p = __builtin_amdgcn_cvt_pkrtz(pa0[3], pa1[3]);
              ah.h2[0] = p0.h; ah.h2[1] = p1.h; ah.h2[2] = p2.h; ah.h2[3] = p3.h;
              *(f16x8*)&Asb[am][ar * 8] = ah.h8; }
            { const uint32_t qq[2] = {pq0, pq1};
#pragma unroll
              for (int rr = 0; rr < 2; ++rr) {
                  const int r = br + rr * 2; H8 bh;
#pragma unroll
                  for (int jp = 0; jp < 4; ++jp) {
                      U32H2 u; u.u = ((qq[rr] >> (4 * jp)) & 0x000F000Fu) | 0x64006400u;
                      bh.h2[jp] = (u.h + hz2) * hs2;
                  }
                  *(f16x8*)&Bsb[bc][(r ^ bswz) * 8] = bh.h8;
              } }
            __syncthreads();
            const int itn = (it < 127) ? it + 1 : 127;
            pa0 = *(const f32x4*)(xrow + itn * 32);
            pa1 = *(const f32x4*)(xrow + itn * 32 + 4);
            pq0 = qweight[(size_t)(itn * 4 + br) * OUTF + bn];
            pq1 = qweight[(size_t)(itn * 4 + br + 2) * OUTF + bn];
            f16x8 af[2], bf[4];
#pragma unroll
            for (int mi = 0; mi < 2; ++mi)
                af[mi] = *(const f16x8*)&Asb[wm * 32 + mi * 16 + l16][quad * 8];
#pragma unroll
            for (int ni = 0; ni < 4; ++ni) {
                const int c = wn * 64 + ni * 16 + l16;
                bf[ni] = *(const f16x8*)&Bsb[c][(quad ^ ((c >> 3) & 3)) * 8];
            }
#pragma unroll
            for (int mi = 0; mi < 2; ++mi)
#pragma unroll
                for (int ni = 0; ni < 4; ++ni)
                    acc[mi][ni] = __builtin_amdgcn_mfma_f32_16x16x32_f16(
                        af[mi], bf[ni], acc[mi][ni], 0, 0, 0);
            __syncthreads();
        }
    }
#pragma unroll
    for (int ni = 0; ni < 4; ++ni) {
        const int col = bx * 128 + wn * 64 + ni * 16 + l16;
        const float bv = bias[col];
#pragma unroll
        for (int mi = 0; mi < 2; ++mi) {
            const int row0 = by * 64 + wm * 32 + mi * 16 + quad * 4;
#pragma unroll
            for (int rg = 0; rg < 4; ++rg)
                out[(size_t)(row0 + rg) * OUTF + col] = acc[mi][ni][rg] + bv;
        }
    }
}

extern "C" void kernel_launch(void* const* d_in, const int* in_sizes, int n_in,
                              void* d_out, int out_size, void* d_ws, size_t ws_size,
                              hipStream_t stream) {
    const float*    xx = (const float*)d_in[0];
    const uint32_t* qw = (const uint32_t*)d_in[1];
    const uint32_t* qz = (const uint32_t*)d_in[2];
    const float*    sc = (const float*)d_in[3];
    const float*    bs = (const float*)d_in[4];
    float* out = (float*)d_out;

    const size_t x16_bytes = (size_t)TOKENS * INF * sizeof(_Float16);  // 2 MB
    if (ws_size >= x16_bytes) {
        _Float16* x16 = (_Float16*)d_ws;
        cvt_x<<<(TOKENS * INF / 8) / NTH, NTH, 0, stream>>>(xx, x16);
        qlin_main<<<(OUTF / 128) * (TOKENS / 64), NTH, 0, stream>>>(x16, qw, qz, sc, bs, out);
    } else {
        dim3 grid(OUTF / 128, TOKENS / 64);
        qlin_fb<<<grid, NTH, 0, stream>>>(xx, qw, qz, sc, bs, out);
    }
}

// Round 7
// 183.401 us; speedup vs baseline: 1.2836x; 1.0740x over previous
//
#include <hip/hip_runtime.h>
#include <stdint.h>

#define TOKENS  256
#define INF     4096
#define OUTF    11008
#define NGROUPS 32
#define NTH     256
#define PHK     64          // k per phase

typedef __attribute__((ext_vector_type(2))) _Float16 f16x2;
typedef __attribute__((ext_vector_type(8))) _Float16 f16x8;
typedef __attribute__((ext_vector_type(2))) __fp16   pkh2;
typedef __attribute__((ext_vector_type(4))) float    f32x4;

union U32H2 { uint32_t u; f16x2 h; };
union H8    { f16x2 h2[4]; f16x8 h8; };
union PK    { pkh2 p; f16x2 h; };

__device__ __forceinline__ void gl2lds16(const void* g, void* l) {
    __builtin_amdgcn_global_load_lds(
        (const __attribute__((address_space(1))) uint32_t*)g,
        (__attribute__((address_space(3))) uint32_t*)l, 16, 0, 0);
}

// ---------------- pre-kernel: x fp32 -> fp16, (j, j+4) pair-permuted ---------
__global__ __launch_bounds__(NTH)
void cvt_x(const float* __restrict__ x, _Float16* __restrict__ x16) {
    const int t   = blockIdx.x * NTH + threadIdx.x;   // 0 .. 131071
    const int row = t >> 9;
    const int c   = t & 511;
    const float* p = x + (size_t)row * INF + c * 8;
    f32x4 v0 = *(const f32x4*)p;
    f32x4 v1 = *(const f32x4*)(p + 4);
    H8 o; PK k0, k1, k2, k3;
    k0.p = __builtin_amdgcn_cvt_pkrtz(v0[0], v1[0]);
    k1.p = __builtin_amdgcn_cvt_pkrtz(v0[1], v1[1]);
    k2.p = __builtin_amdgcn_cvt_pkrtz(v0[2], v1[2]);
    k3.p = __builtin_amdgcn_cvt_pkrtz(v0[3], v1[3]);
    o.h2[0] = k0.h; o.h2[1] = k1.h; o.h2[2] = k2.h; o.h2[3] = k3.h;
    *(f16x8*)(x16 + (size_t)row * INF + c * 8) = o.h8;
}

// ---------------- main kernel: R5 geometry, partials instead of atomics ------
// grid = 86(bx) x 2(by) x KSP(kh) blocks; 256 thr = 2x2 waves of 64x64.
// A staged via gl2lds (2x16KB dbuf, XOR-swizzled, 0 conflicts - R5-verified).
// B dequanted in-register. Partial fp32 tiles streamed to ws (no RMW); a
// separate reduce kernel sums KSP partials + bias. R5's 207MB atomic storm
// (WRITE_SIZE smoking gun) is replaced by 45MB of plain streaming stores.
template<int KSP>
__global__ __launch_bounds__(NTH, 4)
void qlin_part(const _Float16* __restrict__ x16,
               const uint32_t* __restrict__ qweight,
               const uint32_t* __restrict__ qzeros,
               const float* __restrict__ scales,
               float* __restrict__ part)
{
    constexpr int KBLK = INF / KSP;          // k per block
    constexpr int NPH  = KBLK / PHK;         // phases per block
    constexpr int LG   = (KSP == 4) ? 2 : (KSP == 2) ? 1 : 0;

    __shared__ alignas(16) _Float16 As[2][128 * PHK];   // 2 x 16KB

    const int tid = threadIdx.x;
    const int b   = blockIdx.x;
    const int by  = b & 1;                   // adjacent blocks share B fully
    const int kh  = (b >> 1) & (KSP - 1);
    const int bx  = b >> (1 + LG);           // 0..85

    const int lane = tid & 63;
    const int quad = lane >> 4;
    const int l16  = lane & 15;
    const int wv   = tid >> 6;
    const int wr   = wv >> 1;                // row half
    const int wc   = wv & 1;                 // col half

    // ---- A fill map (gl2lds, lane-linear; XOR swizzle by row&7) ----
    const int arow = tid >> 3;               // 0..31 within a 32-row round
    const int lchk = (tid & 7) ^ (arow & 7);
    const char* x16b = (const char*)x16;
    uint32_t aoff[4];
#pragma unroll
    for (int ii = 0; ii < 4; ++ii)
        aoff[ii] = (uint32_t)((by * 128 + ii * 32 + arow) * (INF * 2)
                              + kh * (KBLK * 2) + lchk * 16);
    _Float16* ldsW = &As[0][0];
    const int ldsBase = wv * 512;            // halves

    // ---- B columns ----
    int colN[4];
#pragma unroll
    for (int nf = 0; nf < 4; ++nf)
        colN[nf] = bx * 128 + wc * 64 + nf * 16 + l16;
    const int zsh   = (colN[0] & 7) * 4;
    const int qrow0 = kh * (KBLK / 8);

    f32x4 acc[4][4];
#pragma unroll
    for (int mi = 0; mi < 4; ++mi)
#pragma unroll
        for (int nf = 0; nf < 4; ++nf)
            acc[mi][nf] = f32x4{0.f, 0.f, 0.f, 0.f};

    uint32_t Breg[2][8];      // [par][s*4+nf]
    float    sSc[2][4];       // [par][nf] (1 group per phase-pair, prefetched)
    uint32_t qZr[2][4];

    // ================= prologue: phase 0 =================
#pragma unroll
    for (int ii = 0; ii < 4; ++ii)
        gl2lds16(x16b + aoff[ii], ldsW + ii * 2048 + ldsBase);
#pragma unroll
    for (int s = 0; s < 2; ++s) {
        const uint32_t* qp = qweight + (size_t)(qrow0 + s * 4 + quad) * OUTF;
#pragma unroll
        for (int nf = 0; nf < 4; ++nf)
            Breg[0][s * 4 + nf] = qp[colN[nf]];
    }
    {
        const int g0 = kh * (KBLK / 128);
#pragma unroll
        for (int nf = 0; nf < 4; ++nf) {
            sSc[0][nf] = scales[g0 * OUTF + colN[nf]];
            qZr[0][nf] = qzeros[g0 * (OUTF / 8) + (colN[nf] >> 3)];
        }
    }
    __syncthreads();

    // ================= phase loop (rolled 2x; PAR compile-time) ==============
#define PHASE_BODY(PAR, P, DO_PREFETCH)                                         \
    {                                                                           \
        const int p_ = (P);                                                     \
        if (DO_PREFETCH) {                                                      \
            const int pn = p_ + 1;                                              \
            _Float16* ldsN = ldsW + (1 - (PAR)) * 8192;                         \
            _Pragma("unroll")                                                   \
            for (int ii = 0; ii < 4; ++ii)                                      \
                gl2lds16(x16b + aoff[ii] + pn * (PHK * 2),                      \
                         ldsN + ii * 2048 + ldsBase);                           \
            _Pragma("unroll")                                                   \
            for (int s = 0; s < 2; ++s) {                                       \
                const uint32_t* qp = qweight +                                  \
                    (size_t)(qrow0 + pn * 8 + s * 4 + quad) * OUTF;             \
                _Pragma("unroll")                                               \
                for (int nf = 0; nf < 4; ++nf)                                  \
                    Breg[1 - (PAR)][s * 4 + nf] = qp[colN[nf]];                 \
            }                                                                   \
            const int gn = kh * (KBLK / 128) + (pn >> 1);                       \
            _Pragma("unroll")                                                   \
            for (int nf = 0; nf < 4; ++nf) {                                    \
                sSc[1 - (PAR)][nf] = scales[gn * OUTF + colN[nf]];              \
                qZr[1 - (PAR)][nf] = qzeros[gn * (OUTF / 8)                     \
                                            + (colN[nf] >> 3)];                 \
            }                                                                   \
        }                                                                       \
        f16x2 hs2[4], hz2[4];                                                   \
        _Pragma("unroll")                                                       \
        for (int nf = 0; nf < 4; ++nf) {                                        \
            const float s = sSc[PAR][nf];                                       \
            const int   z = (int)((qZr[PAR][nf] >> zsh) & 15u) + 1025;          \
            const _Float16 hs = (_Float16)s;                                    \
            const _Float16 hz = (_Float16)(-(float)z);                          \
            hs2[nf] = f16x2{hs, hs};                                            \
            hz2[nf] = f16x2{hz, hz};                                            \
        }                                                                       \
        const _Float16* buf = ldsW + (PAR) * 8192;                              \
        _Pragma("unroll")                                                       \
        for (int s = 0; s < 2; ++s) {                                           \
            f16x8 af[4];                                                        \
            _Pragma("unroll")                                                   \
            for (int mi = 0; mi < 4; ++mi) {                                    \
                const int m  = wr * 64 + mi * 16 + l16;                         \
                const int sc = (s * 4 + quad) ^ (l16 & 7);                      \
                af[mi] = *(const f16x8*)(buf + m * PHK + sc * 8);               \
            }                                                                   \
            _Pragma("unroll")                                                   \
            for (int nf = 0; nf < 4; ++nf) {                                    \
                const uint32_t q = Breg[PAR][s * 4 + nf];                       \
                H8 bfr;                                                         \
                _Pragma("unroll")                                               \
                for (int j = 0; j < 4; ++j) {                                   \
                    U32H2 u;                                                    \
                    u.u = ((q >> (4 * j)) & 0x000F000Fu) | 0x64006400u;         \
                    bfr.h2[j] = (u.h + hz2[nf]) * hs2[nf];                      \
                }                                                               \
                _Pragma("unroll")                                               \
                for (int mi = 0; mi < 4; ++mi)                                  \
                    acc[mi][nf] = __builtin_amdgcn_mfma_f32_16x16x32_f16(       \
                        af[mi], bfr.h8, acc[mi][nf], 0, 0, 0);                  \
            }                                                                   \
        }                                                                       \
        __syncthreads();                                                        \
    }

#pragma unroll 1
    for (int pp = 0; pp < NPH / 2; ++pp) {
        PHASE_BODY(0, 2 * pp, true)
        PHASE_BODY(1, 2 * pp + 1, (pp < NPH / 2 - 1))
    }
#undef PHASE_BODY

    // ================= epilogue: stream partial tile (no RMW) =================
    float* wp = part + (size_t)kh * TOKENS * OUTF;
#pragma unroll
    for (int nf = 0; nf < 4; ++nf) {
        const int col = colN[nf];
#pragma unroll
        for (int mi = 0; mi < 4; ++mi) {
            const int r0 = by * 128 + wr * 64 + mi * 16 + quad * 4;
#pragma unroll
            for (int rg = 0; rg < 4; ++rg)
                wp[(size_t)(r0 + rg) * OUTF + col] = acc[mi][nf][rg];
        }
    }
}

// ---------------- reduce: out = sum_kh part[kh] + bias ----------------------
template<int KSP>
__global__ __launch_bounds__(NTH)
void reduce_k(const float* __restrict__ part, const float* __restrict__ bias,
              float* __restrict__ out) {
    constexpr int N4 = TOKENS * OUTF / 4;    // 704512
    const int idx = blockIdx.x * NTH + threadIdx.x;
    const int c4  = idx % (OUTF / 4);
    const f32x4* p4 = (const f32x4*)part;
    f32x4 s = p4[idx];
#pragma unroll
    for (int k = 1; k < KSP; ++k)
        s += p4[(size_t)k * N4 + idx];
    ((f32x4*)out)[idx] = s + ((const f32x4*)bias)[c4];
}

// ---------------- fallback (proven R2 kernel) if ws too small ----------------
__global__ __launch_bounds__(NTH, 2)
void qlin_fb(const float* __restrict__ x,
             const uint32_t* __restrict__ qweight,
             const uint32_t* __restrict__ qzeros,
             const float* __restrict__ scales,
             const float* __restrict__ bias,
             float* __restrict__ out)
{
    __shared__ alignas(16) _Float16 Asb[64][40];
    __shared__ alignas(16) _Float16 Bsb[128][40];
    const int tid = threadIdx.x;
    const int bx = blockIdx.x, by = blockIdx.y;
    const int am = tid >> 2, ar = tid & 3;
    const float* xrow = x + (size_t)(by * 64 + am) * INF + ar * 8;
    const int bc = tid & 127, br = tid >> 7;
    const int bn = bx * 128 + bc;
    const int bswz = (bc >> 3) & 3;
    const int lane = tid & 63, quad = lane >> 4, l16 = lane & 15;
    const int wv = tid >> 6, wm = wv >> 1, wn = wv & 1;
    f32x4 acc[2][4];
#pragma unroll
    for (int i = 0; i < 2; ++i)
#pragma unroll
        for (int j = 0; j < 4; ++j) acc[i][j] = f32x4{0.f, 0.f, 0.f, 0.f};
    f32x4 pa0 = *(const f32x4*)(xrow + 0);
    f32x4 pa1 = *(const f32x4*)(xrow + 4);
    uint32_t pq0 = qweight[(size_t)br * OUTF + bn];
    uint32_t pq1 = qweight[(size_t)(br + 2) * OUTF + bn];
    for (int g = 0; g < NGROUPS; ++g) {
        const float s = scales[g * OUTF + bn];
        const uint32_t qzv = qzeros[g * (OUTF / 8) + (bn >> 3)];
        const int z = (int)((qzv >> (4 * (bn & 7))) & 15u) + 1;
        const _Float16 hs = (_Float16)s;
        const _Float16 hz = (_Float16)(-(float)(1024 + z));
        const f16x2 hs2 = {hs, hs}, hz2 = {hz, hz};
#pragma unroll
        for (int t4 = 0; t4 < 4; ++t4) {
            const int it = (g << 2) + t4;
            { H8 ah; PK p0, p1, p2, p3;
              p0.p = __builtin_amdgcn_cvt_pkrtz(pa0[0], pa1[0]);
              p1.p = __builtin_amdgcn_cvt_pkrtz(pa0[1], pa1[1]);
              p2.p = __builtin_amdgcn_cvt_pkrtz(pa0[2], pa1[2]);
              p3.p = __builtin_amdgcn_cvt_pkrtz(pa0[3], pa1[3]);
              ah.h2[0] = p0.h; ah.h2[1] = p1.h; ah.h2[2] = p2.h; ah.h2[3] = p3.h;
              *(f16x8*)&Asb[am][ar * 8] = ah.h8; }
            { const uint32_t qq[2] = {pq0, pq1};
#pragma unroll
              for (int rr = 0; rr < 2; ++rr) {
                  const int r = br + rr * 2; H8 bh;
#pragma unroll
                  for (int jp = 0; jp < 4; ++jp) {
                      U32H2 u; u.u = ((qq[rr] >> (4 * jp)) & 0x000F000Fu) | 0x64006400u;
                      bh.h2[jp] = (u.h + hz2) * hs2;
                  }
                  *(f16x8*)&Bsb[bc][(r ^ bswz) * 8] = bh.h8;
              } }
            __syncthreads();
            const int itn = (it < 127) ? it + 1 : 127;
            pa0 = *(const f32x4*)(xrow + itn * 32);
            pa1 = *(const f32x4*)(xrow + itn * 32 + 4);
            pq0 = qweight[(size_t)(itn * 4 + br) * OUTF + bn];
            pq1 = qweight[(size_t)(itn * 4 + br + 2) * OUTF + bn];
            f16x8 af[2], bf[4];
#pragma unroll
            for (int mi = 0; mi < 2; ++mi)
                af[mi] = *(const f16x8*)&Asb[wm * 32 + mi * 16 + l16][quad * 8];
#pragma unroll
            for (int ni = 0; ni < 4; ++ni) {
                const int c = wn * 64 + ni * 16 + l16;
                bf[ni] = *(const f16x8*)&Bsb[c][(quad ^ ((c >> 3) & 3)) * 8];
            }
#pragma unroll
            for (int mi = 0; mi < 2; ++mi)
#pragma unroll
                for (int ni = 0; ni < 4; ++ni)
                    acc[mi][ni] = __builtin_amdgcn_mfma_f32_16x16x32_f16(
                        af[mi], bf[ni], acc[mi][ni], 0, 0, 0);
            __syncthreads();
        }
    }
#pragma unroll
    for (int ni = 0; ni < 4; ++ni) {
        const int col = bx * 128 + wn * 64 + ni * 16 + l16;
        const float bv = bias[col];
#pragma unroll
        for (int mi = 0; mi < 2; ++mi) {
            const int row0 = by * 64 + wm * 32 + mi * 16 + quad * 4;
#pragma unroll
            for (int rg = 0; rg < 4; ++rg)
                out[(size_t)(row0 + rg) * OUTF + col] = acc[mi][ni][rg] + bv;
        }
    }
}

extern "C" void kernel_launch(void* const* d_in, const int* in_sizes, int n_in,
                              void* d_out, int out_size, void* d_ws, size_t ws_size,
                              hipStream_t stream) {
    const float*    xx = (const float*)d_in[0];
    const uint32_t* qw = (const uint32_t*)d_in[1];
    const uint32_t* qz = (const uint32_t*)d_in[2];
    const float*    sc = (const float*)d_in[3];
    const float*    bs = (const float*)d_in[4];
    float* out = (float*)d_out;

    constexpr int KSP = 4;
    const size_t x16_bytes  = (size_t)TOKENS * INF * sizeof(_Float16);     // 2 MB
    const size_t part_bytes = (size_t)KSP * TOKENS * OUTF * sizeof(float); // 45 MB

    if (ws_size >= x16_bytes + part_bytes) {
        _Float16* x16  = (_Float16*)d_ws;
        float*    part = (float*)((char*)d_ws + x16_bytes);
        cvt_x<<<(TOKENS * INF / 8) / NTH, NTH, 0, stream>>>(xx, x16);
        qlin_part<KSP><<<(OUTF / 128) * 2 * KSP, NTH, 0, stream>>>(x16, qw, qz, sc, part);
        reduce_k<KSP><<<(TOKENS * OUTF / 4) / NTH, NTH, 0, stream>>>(part, bs, out);
    } else {
        dim3 grid(OUTF / 128, TOKENS / 64);
        qlin_fb<<<grid, NTH, 0, stream>>>(xx, qw, qz, sc, bs, out);
    }
}

// Round 8
// 123.072 us; speedup vs baseline: 1.9128x; 1.4902x over previous
//
#include <hip/hip_runtime.h>
#include <stdint.h>

#define TOKENS  256
#define INF     4096
#define OUTF    11008
#define NGROUPS 32
#define NPHASE  16            // K split into 16 phases of 256
#define NTH     256

typedef __attribute__((ext_vector_type(2))) _Float16 f16x2;
typedef __attribute__((ext_vector_type(8))) _Float16 f16x8;
typedef __attribute__((ext_vector_type(2))) __fp16   pkh2;
typedef __attribute__((ext_vector_type(4))) float    f32x4;

union U32H2 { uint32_t u; f16x2 h; };
union H8    { f16x2 h2[4]; f16x8 h8; };
union PK    { pkh2 p; f16x2 h; };

__device__ __forceinline__ void gl2lds16(const void* g, void* l) {
    __builtin_amdgcn_global_load_lds(
        (const __attribute__((address_space(1))) uint32_t*)g,
        (__attribute__((address_space(3))) uint32_t*)l, 16, 0, 0);
}

// Relaxed barrier: wait for all but the newest N VMEM ops, then s_barrier.
// N = loads issued AFTER the last gl2lds of this phase; vmcnt is issue-ordered,
// so this guarantees gl2lds completion (LDS ready) while keeping the N newest
// register-loads in flight ACROSS the barrier (hipBLASLt pattern; kills the
// ~5k-cyc vmcnt(0) drain that R2/R4/R7 counters pinned as the bottleneck).
#define BARRIER_KEEP24() asm volatile("s_waitcnt vmcnt(24)\n\ts_barrier" ::: "memory")
#define ISSUE_FENCE()    asm volatile("" ::: "memory")

// LDS column swizzle: stored 16B-chunk col = logical ^ F(m&15).
__device__ __forceinline__ int Fswz(int m4) {
    return (m4 & 0xF) | (((m4 ^ (m4 >> 1)) & 1) << 4);
}

// ---------------- pre-kernel: x fp32 -> fp16, (j, j+4) pair-permuted ---------
__global__ __launch_bounds__(NTH)
void cvt_x(const float* __restrict__ x, _Float16* __restrict__ x16) {
    const int t   = blockIdx.x * NTH + threadIdx.x;   // 0 .. 131071
    const int row = t >> 9;
    const int c   = t & 511;
    const float* p = x + (size_t)row * INF + c * 8;
    f32x4 v0 = *(const f32x4*)p;
    f32x4 v1 = *(const f32x4*)(p + 4);
    H8 o; PK k0, k1, k2, k3;
    k0.p = __builtin_amdgcn_cvt_pkrtz(v0[0], v1[0]);
    k1.p = __builtin_amdgcn_cvt_pkrtz(v0[1], v1[1]);
    k2.p = __builtin_amdgcn_cvt_pkrtz(v0[2], v1[2]);
    k3.p = __builtin_amdgcn_cvt_pkrtz(v0[3], v1[3]);
    o.h2[0] = k0.h; o.h2[1] = k1.h; o.h2[2] = k2.h; o.h2[3] = k3.h;
    *(f16x8*)(x16 + (size_t)row * INF + c * 8) = o.h8;
}

// ---------------- main kernel: R4 structure + relaxed barriers ---------------
__global__ __launch_bounds__(NTH, 2)
void qlin_main(const _Float16* __restrict__ x16,
               const uint32_t* __restrict__ qweight,
               const uint32_t* __restrict__ qzeros,
               const float* __restrict__ scales,
               const float* __restrict__ bias,
               float* __restrict__ out)
{
    __shared__ alignas(16) _Float16 As[2][64 * 256];   // 2 x 32KB double buffer

    const int tid = threadIdx.x;
    const int bx  = blockIdx.x >> 2;   // 0..85  (out-feature block)
    const int by  = blockIdx.x & 3;    // 0..3   (token block)

    const int lane = tid & 63;
    const int quad = lane >> 4;
    const int l16  = lane & 15;
    const int wv   = tid >> 6;         // 0..3, wave's 32-col strip

    // ---- A fill map (global_load_lds, lane-linear slots) ----
    const int rowoff = (tid >> 5) & 7;
    const int sclin  = tid & 31;
    const int row0   = by * 64;
    const uint32_t aoffE = (uint32_t)((row0 + rowoff)     * (INF * 2) + (sclin ^ Fswz(rowoff))     * 16);
    const uint32_t aoffO = (uint32_t)((row0 + 8 + rowoff) * (INF * 2) + (sclin ^ Fswz(8 + rowoff)) * 16);
    const char* x16b = (const char*)x16;
    _Float16* ldsW = &As[0][0];
    const int ldsSlotBase = wv * 512;  // halves; + i*2048 per instr; +16384 per buf

    // ---- B map ----
    const int col0 = bx * 128 + wv * 32 + l16;   // nf=0 column
    const int col1 = col0 + 16;                  // nf=1 column
    const int bOff0 = quad * OUTF + col0;
    const int bOff1 = quad * OUTF + col1;
    const int zsh = (col0 & 7) * 4;              // same for col1

    const int fsw = Fswz(l16);

    f32x4 acc[4][2];
#pragma unroll
    for (int mi = 0; mi < 4; ++mi)
#pragma unroll
        for (int nf = 0; nf < 2; ++nf)
            acc[mi][nf] = f32x4{0.f, 0.f, 0.f, 0.f};

    uint32_t Breg[2][16];
    float    sS[2][4];       // [par][gh*2+nf]
    uint32_t qZ[2][4];

    // ================= prologue: phase 0 prefetch =================
#pragma unroll
    for (int ii = 0; ii < 4; ++ii) {
        gl2lds16(x16b + aoffE + ii * 131072, ldsW + (2 * ii)     * 2048 + ldsSlotBase);
        gl2lds16(x16b + aoffO + ii * 131072, ldsW + (2 * ii + 1) * 2048 + ldsSlotBase);
    }
    ISSUE_FENCE();   // pin: 8 gl2lds older than the 24 register-loads below
#pragma unroll
    for (int s = 0; s < 8; ++s) {
        const uint32_t* qp = qweight + (size_t)(s * 4) * OUTF;
        Breg[0][2 * s + 0] = qp[bOff0];
        Breg[0][2 * s + 1] = qp[bOff1];
    }
    sS[0][0] = scales[0 * OUTF + col0]; sS[0][1] = scales[0 * OUTF + col1];
    sS[0][2] = scales[1 * OUTF + col0]; sS[0][3] = scales[1 * OUTF + col1];
    qZ[0][0] = qzeros[0 * (OUTF / 8) + (col0 >> 3)]; qZ[0][1] = qzeros[0 * (OUTF / 8) + (col1 >> 3)];
    qZ[0][2] = qzeros[1 * (OUTF / 8) + (col0 >> 3)]; qZ[0][3] = qzeros[1 * (OUTF / 8) + (col1 >> 3)];
    BARRIER_KEEP24();

    // ================= phase loop (rolled, 2 phases per iteration) ============
#define PHASE_BODY(PAR, P, DO_PREFETCH)                                          \
    {                                                                            \
        const int p_ = (P);                                                      \
        if (DO_PREFETCH) {                                                       \
            const int pn = p_ + 1;                                               \
            const uint32_t pb = (uint32_t)(pn * 512);                            \
            _Float16* ldsN = ldsW + (1 - (PAR)) * 16384;                         \
            _Pragma("unroll")                                                    \
            for (int ii = 0; ii < 4; ++ii) {                                     \
                gl2lds16(x16b + aoffE + ii * 131072 + pb,                        \
                         ldsN + (2 * ii)     * 2048 + ldsSlotBase);              \
                gl2lds16(x16b + aoffO + ii * 131072 + pb,                        \
                         ldsN + (2 * ii + 1) * 2048 + ldsSlotBase);              \
            }                                                                    \
            ISSUE_FENCE();                                                       \
            const uint32_t* qpb = qweight + (size_t)(pn * 32) * OUTF;            \
            _Pragma("unroll")                                                    \
            for (int s = 0; s < 8; ++s) {                                        \
                const uint32_t* qp = qpb + (size_t)(s * 4) * OUTF;               \
                Breg[1 - (PAR)][2 * s + 0] = qp[bOff0];                          \
                Breg[1 - (PAR)][2 * s + 1] = qp[bOff1];                          \
            }                                                                    \
            const int g0 = 2 * pn, g1 = 2 * pn + 1;                              \
            sS[1 - (PAR)][0] = scales[g0 * OUTF + col0];                         \
            sS[1 - (PAR)][1] = scales[g0 * OUTF + col1];                         \
            sS[1 - (PAR)][2] = scales[g1 * OUTF + col0];                         \
            sS[1 - (PAR)][3] = scales[g1 * OUTF + col1];                         \
            qZ[1 - (PAR)][0] = qzeros[g0 * (OUTF / 8) + (col0 >> 3)];            \
            qZ[1 - (PAR)][1] = qzeros[g0 * (OUTF / 8) + (col1 >> 3)];            \
            qZ[1 - (PAR)][2] = qzeros[g1 * (OUTF / 8) + (col0 >> 3)];            \
            qZ[1 - (PAR)][3] = qzeros[g1 * (OUTF / 8) + (col1 >> 3)];            \
        }                                                                        \
        f16x2 hs2[2][2], hz2[2][2];                                              \
        _Pragma("unroll")                                                        \
        for (int gh = 0; gh < 2; ++gh)                                           \
            _Pragma("unroll")                                                    \
            for (int nf = 0; nf < 2; ++nf) {                                     \
                const float s = sS[PAR][gh * 2 + nf];                            \
                const int   z = (int)((qZ[PAR][gh * 2 + nf] >> zsh) & 15u) + 1025; \
                const _Float16 hs = (_Float16)s;                                 \
                const _Float16 hz = (_Float16)(-(float)z);                       \
                hs2[gh][nf] = f16x2{hs, hs};                                     \
                hz2[gh][nf] = f16x2{hz, hz};                                     \
            }                                                                    \
        const _Float16* buf = ldsW + (PAR) * 16384;                              \
        _Pragma("unroll")                                                        \
        for (int s = 0; s < 8; ++s) {                                            \
            const int gh = s >> 2;                                               \
            f16x8 af[4];                                                         \
            _Pragma("unroll")                                                    \
            for (int mi = 0; mi < 4; ++mi) {                                     \
                const int m  = mi * 16 + l16;                                    \
                const int sc = (s * 4 + quad) ^ fsw;                             \
                af[mi] = *(const f16x8*)(buf + m * 256 + sc * 8);                \
            }                                                                    \
            _Pragma("unroll")                                                    \
            for (int nf = 0; nf < 2; ++nf) {                                     \
                const uint32_t q = Breg[PAR][2 * s + nf];                        \
                H8 b;                                                            \
                _Pragma("unroll")                                                \
                for (int j = 0; j < 4; ++j) {                                    \
                    U32H2 u;                                                     \
                    u.u = ((q >> (4 * j)) & 0x000F000Fu) | 0x64006400u;          \
                    b.h2[j] = (u.h + hz2[gh][nf]) * hs2[gh][nf];                 \
                }                                                                \
                _Pragma("unroll")                                                \
                for (int mi = 0; mi < 4; ++mi)                                   \
                    acc[mi][nf] = __builtin_amdgcn_mfma_f32_16x16x32_f16(        \
                        af[mi], b.h8, acc[mi][nf], 0, 0, 0);                     \
            }                                                                    \
        }                                                                        \
        if (DO_PREFETCH) { BARRIER_KEEP24(); }                                   \
        /* last phase: no barrier needed, epilogue follows */                    \
    }

#pragma unroll 1
    for (int pp = 0; pp < NPHASE / 2; ++pp) {
        PHASE_BODY(0, 2 * pp, true)
        PHASE_BODY(1, 2 * pp + 1, (pp < NPHASE / 2 - 1))
    }
#undef PHASE_BODY

    // ================= epilogue =================
#pragma unroll
    for (int nf = 0; nf < 2; ++nf) {
        const int col = (nf == 0) ? col0 : col1;
        const float bv = bias[col];
#pragma unroll
        for (int mi = 0; mi < 4; ++mi) {
            const int r0 = by * 64 + mi * 16 + quad * 4;
#pragma unroll
            for (int rg = 0; rg < 4; ++rg)
                out[(size_t)(r0 + rg) * OUTF + col] = acc[mi][nf][rg] + bv;
        }
    }
}

// ---------------- fallback (proven R2 kernel) if ws too small ----------------
__global__ __launch_bounds__(NTH, 2)
void qlin_fb(const float* __restrict__ x,
             const uint32_t* __restrict__ qweight,
             const uint32_t* __restrict__ qzeros,
             const float* __restrict__ scales,
             const float* __restrict__ bias,
             float* __restrict__ out)
{
    __shared__ alignas(16) _Float16 Asb[64][40];
    __shared__ alignas(16) _Float16 Bsb[128][40];
    const int tid = threadIdx.x;
    const int bx = blockIdx.x, by = blockIdx.y;
    const int am = tid >> 2, ar = tid & 3;
    const float* xrow = x + (size_t)(by * 64 + am) * INF + ar * 8;
    const int bc = tid & 127, br = tid >> 7;
    const int bn = bx * 128 + bc;
    const int bswz = (bc >> 3) & 3;
    const int lane = tid & 63, quad = lane >> 4, l16 = lane & 15;
    const int wv = tid >> 6, wm = wv >> 1, wn = wv & 1;
    f32x4 acc[2][4];
#pragma unroll
    for (int i = 0; i < 2; ++i)
#pragma unroll
        for (int j = 0; j < 4; ++j) acc[i][j] = f32x4{0.f, 0.f, 0.f, 0.f};
    f32x4 pa0 = *(const f32x4*)(xrow + 0);
    f32x4 pa1 = *(const f32x4*)(xrow + 4);
    uint32_t pq0 = qweight[(size_t)br * OUTF + bn];
    uint32_t pq1 = qweight[(size_t)(br + 2) * OUTF + bn];
    for (int g = 0; g < NGROUPS; ++g) {
        const float s = scales[g * OUTF + bn];
        const uint32_t qzv = qzeros[g * (OUTF / 8) + (bn >> 3)];
        const int z = (int)((qzv >> (4 * (bn & 7))) & 15u) + 1;
        const _Float16 hs = (_Float16)s;
        const _Float16 hz = (_Float16)(-(float)(1024 + z));
        const f16x2 hs2 = {hs, hs}, hz2 = {hz, hz};
#pragma unroll
        for (int t4 = 0; t4 < 4; ++t4) {
            const int it = (g << 2) + t4;
            { H8 ah; PK p0, p1, p2, p3;
              p0.p = __builtin_amdgcn_cvt_pkrtz(pa0[0], pa1[0]);
              p1.p = __builtin_amdgcn_cvt_pkrtz(pa0[1], pa1[1]);
              p2.p = __builtin_amdgcn_cvt_pkrtz(pa0[2], pa1[2]);
              p3.p = __builtin_amdgcn_cvt_pkrtz(pa0[3], pa1[3]);
              ah.h2[0] = p0.h; ah.h2[1] = p1.h; ah.h2[2] = p2.h; ah.h2[3] = p3.h;
              *(f16x8*)&Asb[am][ar * 8] = ah.h8; }
            { const uint32_t qq[2] = {pq0, pq1};
#pragma unroll
              for (int rr = 0; rr < 2; ++rr) {
                  const int r = br + rr * 2; H8 bh;
#pragma unroll
                  for (int jp = 0; jp < 4; ++jp) {
                      U32H2 u; u.u = ((qq[rr] >> (4 * jp)) & 0x000F000Fu) | 0x64006400u;
                      bh.h2[jp] = (u.h + hz2) * hs2;
                  }
                  *(f16x8*)&Bsb[bc][(r ^ bswz) * 8] = bh.h8;
              } }
            __syncthreads();
            const int itn = (it < 127) ? it + 1 : 127;
            pa0 = *(const f32x4*)(xrow + itn * 32);
            pa1 = *(const f32x4*)(xrow + itn * 32 + 4);
            pq0 = qweight[(size_t)(itn * 4 + br) * OUTF + bn];
            pq1 = qweight[(size_t)(itn * 4 + br + 2) * OUTF + bn];
            f16x8 af[2], bf[4];
#pragma unroll
            for (int mi = 0; mi < 2; ++mi)
                af[mi] = *(const f16x8*)&Asb[wm * 32 + mi * 16 + l16][quad * 8];
#pragma unroll
            for (int ni = 0; ni < 4; ++ni) {
                const int c = wn * 64 + ni * 16 + l16;
                bf[ni] = *(const f16x8*)&Bsb[c][(quad ^ ((c >> 3) & 3)) * 8];
            }
#pragma unroll
            for (int mi = 0; mi < 2; ++mi)
#pragma unroll
                for (int ni = 0; ni < 4; ++ni)
                    acc[mi][ni] = __builtin_amdgcn_mfma_f32_16x16x32_f16(
                        af[mi], bf[ni], acc[mi][ni], 0, 0, 0);
            __syncthreads();
        }
    }
#pragma unroll
    for (int ni = 0; ni < 4; ++ni) {
        const int col = bx * 128 + wn * 64 + ni * 16 + l16;
        const float bv = bias[col];
#pragma unroll
        for (int mi = 0; mi < 2; ++mi) {
            const int row0 = by * 64 + wm * 32 + mi * 16 + quad * 4;
#pragma unroll
            for (int rg = 0; rg < 4; ++rg)
                out[(size_t)(row0 + rg) * OUTF + col] = acc[mi][ni][rg] + bv;
        }
    }
}

extern "C" void kernel_launch(void* const* d_in, const int* in_sizes, int n_in,
                              void* d_out, int out_size, void* d_ws, size_t ws_size,
                              hipStream_t stream) {
    const float*    xx = (const float*)d_in[0];
    const uint32_t* qw = (const uint32_t*)d_in[1];
    const uint32_t* qz = (const uint32_t*)d_in[2];
    const float*    sc = (const float*)d_in[3];
    const float*    bs = (const float*)d_in[4];
    float* out = (float*)d_out;

    const size_t x16_bytes = (size_t)TOKENS * INF * sizeof(_Float16);  // 2 MB
    if (ws_size >= x16_bytes) {
        _Float16* x16 = (_Float16*)d_ws;
        cvt_x<<<(TOKENS * INF / 8) / NTH, NTH, 0, stream>>>(xx, x16);
        qlin_main<<<(OUTF / 128) * (TOKENS / 64), NTH, 0, stream>>>(x16, qw, qz, sc, bs, out);
    } else {
        dim3 grid(OUTF / 128, TOKENS / 64);
        qlin_fb<<<grid, NTH, 0, stream>>>(xx, qw, qz, sc, bs, out);
    }
}